// Round 3
// baseline (2295.770 us; speedup 1.0000x reference)
//
#include <hip/hip_runtime.h>

#define Hh 1024
#define NBATCH 128
#define TSTEPS 256
#define DOUT 1024
#define SLOT (NBATCH * Hh)

typedef _Float16 half8 __attribute__((ext_vector_type(8)));
typedef float floatx4 __attribute__((ext_vector_type(4)));
typedef unsigned int uint4v __attribute__((ext_vector_type(4)));

__device__ __forceinline__ float fast_sigmoid(float x) {
  float e = __expf(-x);
  return __builtin_amdgcn_rcpf(1.0f + e);
}
__device__ __forceinline__ float fast_tanh(float x) {
  x = fminf(15.0f, fmaxf(-15.0f, x));
  float e = __expf(-2.0f * x);
  return 1.0f - 2.0f * e * __builtin_amdgcn_rcpf(1.0f + e);
}

// Encode an f16 bit pattern for the write-once "data is the flag" ring:
// canonicalize -0 -> +0, then flip the sign bit. Resulting u16 is NEVER 0,
// so a zero u16 in the ring means "not written yet". Decode = XOR 0x8000
// (bit-exact except -0 -> +0, numerically identical).
__device__ __forceinline__ unsigned short enc_h(float h) {
  _Float16 hv = (_Float16)h;
  unsigned short ub;
  __builtin_memcpy(&ub, &hv, 2);
  if (ub == 0x8000u) ub = 0u;
  return (unsigned short)(ub ^ 0x8000u);
}

// Convert weights to f16, build W_sum = W_ih + W_hh, b_sum = b_ih + b_hh,
// stage hT ENCODED into hs slot 0, ZERO hs slots 1..256 (poll sentinels),
// zero flags (xcd counters).
__global__ void prep_kernel(const float* __restrict__ W_ih, const float* __restrict__ W_hh,
                            const float* __restrict__ W_fc, const float* __restrict__ b_ih,
                            const float* __restrict__ b_hh, const float* __restrict__ hT,
                            _Float16* __restrict__ w_ih_h, _Float16* __restrict__ w_sum_h,
                            _Float16* __restrict__ w_fc_h, float* __restrict__ b_sum,
                            _Float16* __restrict__ hs0, unsigned* __restrict__ flags) {
  int i0 = blockIdx.x * blockDim.x + threadIdx.x;
  int stride = gridDim.x * blockDim.x;
  for (int i = i0; i < 4096 * 1024; i += stride) {
    float a = W_ih[i];
    w_ih_h[i] = (_Float16)a;
    w_sum_h[i] = (_Float16)(a + W_hh[i]);
  }
  for (int i = i0; i < 1024 * 1024; i += stride) w_fc_h[i] = (_Float16)W_fc[i];
  for (int i = i0; i < 4096; i += stride) b_sum[i] = b_ih[i] + b_hh[i];
  // slot 0 = encoded hT
  unsigned short* h0 = (unsigned short*)hs0;
  for (int i = i0; i < NBATCH * Hh; i += stride) h0[i] = enc_h(hT[i]);
  // slots 1..256 zeroed (sentinel = u16 0x0000)
  unsigned* zp = (unsigned*)(hs0 + SLOT);
  for (int i = i0; i < (TSTEPS * SLOT) / 2; i += stride) zp[i] = 0u;
  for (int i = i0; i < 512; i += stride) flags[i] = 0;
}

// Persistent LSTM kernel: 256 WGs (one per CU), 4 waves each, XCD-local
// groups via HW_REG_XCC_ID self-assignment (v2-proven: FETCH 275->98MB).
//
// Synchronization: DATA IS THE FLAG. h values are stored sign-flip-encoded
// (never-zero u16) with AGENT-scope write-through stores; consumers poll
// their exact A-fragments with sc0 sc1 (coherence-point) dwordx4 loads
// until no u16 is zero, then XOR-decode and MFMA the polled registers
// directly. This removes the v2 chain's store-drain, flag-store and
// separate A-load hops (each ~1.5-2K cycles of L3 latency).
// No vmcnt drains remain: barriers are raw s_barrier + lgkmcnt(0) only,
// and the LDS reduce buffer is double-buffered so ONE barrier per step
// suffices (waves stay within one step of each other; writers touch pb,
// stragglers read pb^1).
__global__ __launch_bounds__(256, 1) void lstm_kernel(
    const _Float16* __restrict__ w_ih_h, const _Float16* __restrict__ w_sum_h,
    const float* __restrict__ b_sum, _Float16* __restrict__ hs,
    unsigned* __restrict__ flags) {
  unsigned* xcd_ctr = flags + 256;
  const int tid = threadIdx.x;
  const int wave = tid >> 6;
  const int lane = tid & 63;
  const int l15 = lane & 15;
  const int quad = lane >> 4;

  __shared__ unsigned role_sh;
  {
    unsigned xcd;
    asm volatile("s_getreg_b32 %0, hwreg(HW_REG_XCC_ID)" : "=s"(xcd));
    if (tid == 0) role_sh = (xcd << 8) | atomicAdd(&xcd_ctr[xcd], 1u);
  }
  __syncthreads();
  const int g = role_sh >> 8;    // physical XCD == n-group
  const int jb = role_sh & 255;  // 0..31 within the XCD
  const int n0 = g * 16;
  const int j0 = jb * 32;
  const int kbase = wave * 256;
  const int oc = wave >> 1;  // ct half this wave reduces/owns
  const int rp = wave & 1;   // accumulator reg-pair this wave reduces/owns

  __shared__ float2 part[2][4][2][4][2][64];  // [pb][src][ct][gate][rpair][lane] = 64KB

  float bias[4];
#pragma unroll
  for (int gt = 0; gt < 4; ++gt) bias[gt] = b_sum[gt * 1024 + j0 + oc * 16 + l15];

  half8 B[4][2][8];             // 256 regs of resident weights per lane
  float cst[2] = {0.0f, 0.0f};  // persistent cell state (this thread's 2 slots)

  auto load_B = [&](const _Float16* w) {
#pragma unroll
    for (int gt = 0; gt < 4; ++gt)
#pragma unroll
      for (int ct = 0; ct < 2; ++ct) {
        const _Float16* p =
            w + (size_t)(gt * 1024 + j0 + ct * 16 + l15) * Hh + kbase + quad * 8;
#pragma unroll
        for (int ks = 0; ks < 8; ++ks) B[gt][ct][ks] = *(const half8*)(p + ks * 32);
      }
  };

  auto do_step = [&](const _Float16* hsrc, _Float16* hdst, int pb) {
    const unsigned long long va =
        (unsigned long long)(hsrc + (size_t)(n0 + l15) * Hh + kbase + quad * 8);
    uint4v q0, q1, q2, q3, q4, q5, q6, q7;
    const uint4v C1 = {0x00010001u, 0x00010001u, 0x00010001u, 0x00010001u};
    const uint4v HB = {0x80008000u, 0x80008000u, 0x80008000u, 0x80008000u};
    while (1) {
      asm volatile("global_load_dwordx4 %0, %1, off sc0 sc1" : "=&v"(q0) : "v"(va));
      asm volatile("global_load_dwordx4 %0, %1, off offset:64 sc0 sc1" : "=&v"(q1) : "v"(va));
      asm volatile("global_load_dwordx4 %0, %1, off offset:128 sc0 sc1" : "=&v"(q2) : "v"(va));
      asm volatile("global_load_dwordx4 %0, %1, off offset:192 sc0 sc1" : "=&v"(q3) : "v"(va));
      asm volatile("global_load_dwordx4 %0, %1, off offset:256 sc0 sc1" : "=&v"(q4) : "v"(va));
      asm volatile("global_load_dwordx4 %0, %1, off offset:320 sc0 sc1" : "=&v"(q5) : "v"(va));
      asm volatile("global_load_dwordx4 %0, %1, off offset:384 sc0 sc1" : "=&v"(q6) : "v"(va));
      asm volatile("global_load_dwordx4 %0, %1, off offset:448 sc0 sc1" : "=&v"(q7) : "v"(va));
      asm volatile("s_waitcnt vmcnt(0)" ::: "memory");
      __builtin_amdgcn_sched_barrier(0);
      // haszero16(v) = (v - 0x00010001) & ~v & 0x80008000 (no false pos/neg)
      uint4v z = ((q0 - C1) & ~q0) | ((q1 - C1) & ~q1) | ((q2 - C1) & ~q2) |
                 ((q3 - C1) & ~q3) | ((q4 - C1) & ~q4) | ((q5 - C1) & ~q5) |
                 ((q6 - C1) & ~q6) | ((q7 - C1) & ~q7);
      z &= HB;
      if (__all((int)((z.x | z.y | z.z | z.w) == 0u))) break;
    }
    half8 Af[8];
    Af[0] = __builtin_bit_cast(half8, q0 ^ HB);
    Af[1] = __builtin_bit_cast(half8, q1 ^ HB);
    Af[2] = __builtin_bit_cast(half8, q2 ^ HB);
    Af[3] = __builtin_bit_cast(half8, q3 ^ HB);
    Af[4] = __builtin_bit_cast(half8, q4 ^ HB);
    Af[5] = __builtin_bit_cast(half8, q5 ^ HB);
    Af[6] = __builtin_bit_cast(half8, q6 ^ HB);
    Af[7] = __builtin_bit_cast(half8, q7 ^ HB);

    floatx4 acc[2][4] = {};
#pragma unroll
    for (int ks = 0; ks < 8; ++ks)
#pragma unroll
      for (int ct = 0; ct < 2; ++ct)
#pragma unroll
        for (int gt = 0; gt < 4; ++gt)
          acc[ct][gt] =
              __builtin_amdgcn_mfma_f32_16x16x32_f16(Af[ks], B[gt][ct][ks], acc[ct][gt], 0, 0, 0);

#pragma unroll
    for (int ct = 0; ct < 2; ++ct)
#pragma unroll
      for (int gt = 0; gt < 4; ++gt) {
        float2 lo, hi;
        lo.x = acc[ct][gt][0]; lo.y = acc[ct][gt][1];
        hi.x = acc[ct][gt][2]; hi.y = acc[ct][gt][3];
        part[pb][wave][ct][gt][0][lane] = lo;
        part[pb][wave][ct][gt][1][lane] = hi;
      }
    // LDS writes visible, then single barrier (NO vmcnt drain -- h stores fly).
    asm volatile("s_waitcnt lgkmcnt(0)" ::: "memory");
    __builtin_amdgcn_sched_barrier(0);
    __builtin_amdgcn_s_barrier();
    __builtin_amdgcn_sched_barrier(0);

    float gv[4][2];
#pragma unroll
    for (int gt = 0; gt < 4; ++gt) {
      float2 s = part[pb][0][oc][gt][rp][lane];
#pragma unroll
      for (int src = 1; src < 4; ++src) {
        float2 p = part[pb][src][oc][gt][rp][lane];
        s.x += p.x; s.y += p.y;
      }
      gv[gt][0] = s.x + bias[gt];
      gv[gt][1] = s.y + bias[gt];
    }
#pragma unroll
    for (int rr = 0; rr < 2; ++rr) {
      float ig = fast_sigmoid(gv[0][rr]);
      float fg = fast_sigmoid(gv[1][rr]);
      float gg = fast_tanh(gv[2][rr]);
      float og = fast_sigmoid(gv[3][rr]);
      float c = fg * cst[rr] + ig * gg;
      cst[rr] = c;
      float h = og * fast_tanh(c);
      int row = n0 + quad * 4 + rp * 2 + rr;
      unsigned short ub = enc_h(h);
      // AGENT write-through store: lands at the coherence point in flight;
      // consumers' sc0 sc1 polls observe it without any producer-side drain.
      __hip_atomic_store((unsigned short*)(hdst + (size_t)row * Hh + j0 + oc * 16 + l15),
                         ub, __ATOMIC_RELAXED, __HIP_MEMORY_SCOPE_AGENT);
    }
  };

  // Step 0: x = hT (encoded in slot 0), hx = 0 => gates = hT @ W_ih^T + b_sum
  load_B(w_ih_h);
  do_step(hs, hs + SLOT, 0);
  // Steps 1..255: x = hx = h => gates = h @ (W_ih+W_hh)^T + b_sum
  load_B(w_sum_h);
  for (int s = 1; s < TSTEPS; ++s)
    do_step(hs + (size_t)s * SLOT, hs + (size_t)(s + 1) * SLOT, s & 1);
}

// recons[n, s, :] = h_s @ W_fc^T + b_fc.  A = hs slots 1..256 viewed as
// [32768 x 1024] ENCODED f16 (row r = s*128 + n); decode = XOR 0x8000/u16.
__global__ __launch_bounds__(256) void fc_kernel(const _Float16* __restrict__ A,
                                                 const _Float16* __restrict__ Bw,
                                                 const float* __restrict__ b_fc,
                                                 float* __restrict__ out) {
  const int nb = blockIdx.x;  // 0..15  (d blocks of 64)
  const int mb = blockIdx.y;  // 0..511 (row blocks of 64)
  const int tid = threadIdx.x;
  const int wave = tid >> 6;
  const int lane = tid & 63;
  const int l15 = lane & 15;
  const int quad = lane >> 4;
  const int m0 = mb * 64 + wave * 16;
  const int d0 = nb * 64;
  const uint4v HB = {0x80008000u, 0x80008000u, 0x80008000u, 0x80008000u};

  floatx4 acc[4] = {};
  const _Float16* ap = A + (size_t)(m0 + l15) * Hh + quad * 8;
  const _Float16* bp = Bw + (size_t)(d0 + l15) * Hh + quad * 8;
#pragma unroll 4
  for (int k = 0; k < Hh; k += 32) {
    uint4v t = *(const uint4v*)(ap + k);
    half8 a = __builtin_bit_cast(half8, t ^ HB);
#pragma unroll
    for (int ct = 0; ct < 4; ++ct) {
      half8 b = *(const half8*)(bp + (size_t)ct * 16 * Hh + k);
      acc[ct] = __builtin_amdgcn_mfma_f32_16x16x32_f16(a, b, acc[ct], 0, 0, 0);
    }
  }
#pragma unroll
  for (int ct = 0; ct < 4; ++ct) {
    int d = d0 + ct * 16 + l15;
    float bv = b_fc[d];
#pragma unroll
    for (int r = 0; r < 4; ++r) {
      int row = m0 + quad * 4 + r;
      int s = row >> 7;
      int n = row & 127;
      out[((size_t)n * TSTEPS + s) * DOUT + d] = acc[ct][r] + bv;
    }
  }
}

extern "C" void kernel_launch(void* const* d_in, const int* in_sizes, int n_in,
                              void* d_out, int out_size, void* d_ws, size_t ws_size,
                              hipStream_t stream) {
  const float* hT   = (const float*)d_in[0];
  const float* W_ih = (const float*)d_in[1];
  const float* W_hh = (const float*)d_in[2];
  const float* b_ih = (const float*)d_in[3];
  const float* b_hh = (const float*)d_in[4];
  const float* W_fc = (const float*)d_in[5];
  const float* b_fc = (const float*)d_in[6];
  float* out = (float*)d_out;

  char* ws = (char*)d_ws;
  unsigned* flags   = (unsigned*)ws;                    // xcd counters live at +256
  float* b_sum      = (float*)(ws + 4096);              // 16KB
  _Float16* w_ih_h  = (_Float16*)(ws + 65536);          // 8MB
  _Float16* w_sum_h = w_ih_h + (size_t)4096 * 1024;     // 8MB
  _Float16* w_fc_h  = w_sum_h + (size_t)4096 * 1024;    // 2MB
  _Float16* hs      = w_fc_h + (size_t)1024 * 1024;     // 257 * 256KB = 67.3MB

  prep_kernel<<<4096, 256, 0, stream>>>(W_ih, W_hh, W_fc, b_ih, b_hh, hT,
                                        w_ih_h, w_sum_h, w_fc_h, b_sum, hs, flags);
  lstm_kernel<<<256, 256, 0, stream>>>(w_ih_h, w_sum_h, b_sum, hs, flags);
  fc_kernel<<<dim3(16, 512), 256, 0, stream>>>(hs + SLOT, w_fc_h, b_fc, out);
}